// Round 2
// baseline (2771.854 us; speedup 1.0000x reference)
//
#include <hip/hip_runtime.h>

// ---------------- bf16 helpers (bit-level, no header dependency) ------------
__device__ __forceinline__ short f2bf(float f) {       // RNE f32 -> bf16
    unsigned u = __float_as_uint(f);
    unsigned r = (u + 0x7FFFu + ((u >> 16) & 1u)) >> 16;
    return (short)r;
}
__device__ __forceinline__ float bf2f(short s) {
    return __uint_as_float(((unsigned)(unsigned short)s) << 16);
}

typedef short bf16x8 __attribute__((ext_vector_type(8)));
typedef float f32x4  __attribute__((ext_vector_type(4)));

// async global->LDS, 16B per lane (wave-uniform LDS base + lane*16)
__device__ __forceinline__ void async16(const void* g, void* l) {
    __builtin_amdgcn_global_load_lds(
        (__attribute__((address_space(1))) unsigned int*)(void*)(g),
        (__attribute__((address_space(3))) unsigned int*)(l), 16, 0, 0);
}

#define BAR()    __builtin_amdgcn_s_barrier()
#define SCHED0() __builtin_amdgcn_sched_barrier(0)
#define VMW(n)   asm volatile("s_waitcnt vmcnt(" #n ")" ::: "memory")

// ---------------- generic 128x128x(BK=64) bf16 MFMA GEMM --------------------
// (kept for the small GEMMs: erep, attn1/2 (N=400), final N=51)
// C[m,n] = sum_k A[m,k]*Bt[n,k] + bias[n], with per-MODE epilogue.
// LDS layout is XOR-swizzled in 16B chunks: LDS[r][c] = global[r][c^(r&7)]
// MODE 0: out bf16 = acc+bias
// MODE 1: out bf16 = relu(acc+bias)
// MODE 2: out bf16 = relu((acc+bias)*gate[m,n]); also gate_bf[m,n]=bf16(gate)
// MODE 3: out f32  = acc+bias+freq[fidx[m]*51+n]   (final, nreal=51)
template<int MODE>
__global__ __launch_bounds__(256)
void gemm128(const short* __restrict__ A, long lda,
             const short* __restrict__ B,          // Bt: N rows x K cols
             const float* __restrict__ bias,
             void* __restrict__ outp, long ldo, int ooff, int nreal,
             const float* __restrict__ gate, short* __restrict__ gate_bf,
             const int* __restrict__ fidx, const float* __restrict__ freq,
             int K)
{
    __shared__ short As[128 * 64];
    __shared__ short Bs[128 * 64];
    const int t = threadIdx.x;
    const int lane = t & 63;
    const int w = t >> 6;
    const long bm = (long)blockIdx.y * 128;
    const long bn = (long)blockIdx.x * 128;

    f32x4 acc[4][4] = {};

    const short* Ab = A + bm * lda;
    const short* Bb = B + bn * (long)K;

    const int wm = (w & 1) * 64, wn = (w >> 1) * 64;
    const int mrow = lane & 15, khi = (lane >> 4) * 8;
    const int swz = mrow & 7;          // row-dependent chunk swizzle

    for (int k0 = 0; k0 < K; k0 += 64) {
        __syncthreads();
        #pragma unroll
        for (int i = 0; i < 4; ++i) {
            int idx = i * 256 + t;
            int r = idx >> 3, ch = (idx & 7) ^ (r & 7);
            async16(Ab + (long)r * lda + (k0 + ch * 8), &As[idx * 8]);
        }
        #pragma unroll
        for (int i = 0; i < 4; ++i) {
            int idx = i * 256 + t;
            int r = idx >> 3, ch = (idx & 7) ^ (r & 7);
            async16(Bb + (long)r * K + (k0 + ch * 8), &Bs[idx * 8]);
        }
        __syncthreads();

        #pragma unroll
        for (int kk = 0; kk < 64; kk += 32) {
            const int ch = (((kk + khi) >> 3) ^ swz) * 8;
            bf16x8 a[4], b[4];
            #pragma unroll
            for (int im = 0; im < 4; ++im)
                a[im] = *(const bf16x8*)&As[(wm + im * 16 + mrow) * 64 + ch];
            #pragma unroll
            for (int in = 0; in < 4; ++in)
                b[in] = *(const bf16x8*)&Bs[(wn + in * 16 + mrow) * 64 + ch];
            #pragma unroll
            for (int im = 0; im < 4; ++im)
                #pragma unroll
                for (int in = 0; in < 4; ++in)
                    acc[im][in] = __builtin_amdgcn_mfma_f32_16x16x32_bf16(
                        a[im], b[in], acc[im][in], 0, 0, 0);
        }
    }

    const int col = lane & 15, rb = (lane >> 4) * 4;
    #pragma unroll
    for (int in = 0; in < 4; ++in) {
        long n = bn + wn + in * 16 + col;
        if (n >= nreal) continue;
        float bv = bias[n];
        #pragma unroll
        for (int im = 0; im < 4; ++im) {
            #pragma unroll
            for (int r = 0; r < 4; ++r) {
                long m = bm + wm + im * 16 + rb + r;
                float v = acc[im][in][r] + bv;
                if (MODE == 1) v = fmaxf(v, 0.f);
                if (MODE == 2) {
                    float g = gate[m * 4096 + n];
                    gate_bf[m * 4096 + n] = f2bf(g);
                    v = fmaxf(v * g, 0.f);
                }
                if (MODE == 3) {
                    v += freq[(long)fidx[m] * 51 + n];
                    ((float*)outp)[m * 51 + n] = v;
                } else {
                    ((short*)outp)[m * ldo + ooff + n] = f2bf(v);
                }
            }
        }
    }
}

// ------------- 256x256x(BK=64) 8-wave 8-phase pipelined bf16 GEMM -----------
// ONE barrier per phase: only true syncs are (a) fresh-tile reads after all
// waves' VMW (VMW at p4/p8 end -> p5/p1 entry barrier) and (b) stg overwrite
// >=1 barrier after the region's last ds_read (audited per region). Waves
// drift within a phase so the per-CU LDS pipe overlaps the MFMA pipe; the
// compiler emits counted lgkmcnt waits for each wave's own fragments.
// sched_barrier(0) after each s_barrier pins reads from hoisting above it.
template<int MH>
__device__ __forceinline__ void loadAf(bf16x8 (&a)[4][2], const short* Asb,
                                       int wrow, int fr, int kc0) {
    #pragma unroll
    for (int im = 0; im < 4; ++im) {
        int r = wrow * 128 + MH * 64 + im * 16 + fr;
        const short* rp = Asb + r * 64;
        int s = r & 7;
        a[im][0] = *(const bf16x8*)(rp + ((kc0    ) ^ s) * 8);
        a[im][1] = *(const bf16x8*)(rp + ((kc0 + 4) ^ s) * 8);
    }
}
template<int NH>
__device__ __forceinline__ void loadBf(bf16x8 (&bb)[2][2], const short* Bsb,
                                       int wcol, int fr, int kc0) {
    #pragma unroll
    for (int in = 0; in < 2; ++in) {
        int r = wcol * 64 + NH * 32 + in * 16 + fr;
        const short* rp = Bsb + r * 64;
        int s = r & 7;
        bb[in][0] = *(const bf16x8*)(rp + ((kc0    ) ^ s) * 8);
        bb[in][1] = *(const bf16x8*)(rp + ((kc0 + 4) ^ s) * 8);
    }
}
template<int MH, int NH>
__device__ __forceinline__ void quadf(f32x4 (&acc)[8][4], const bf16x8 (&a)[4][2],
                                      const bf16x8 (&bb)[2][2]) {
    #pragma unroll
    for (int ks = 0; ks < 2; ++ks)
        #pragma unroll
        for (int im = 0; im < 4; ++im)
            #pragma unroll
            for (int in = 0; in < 2; ++in)
                acc[MH * 4 + im][NH * 2 + in] = __builtin_amdgcn_mfma_f32_16x16x32_bf16(
                    a[im][ks], bb[in][ks], acc[MH * 4 + im][NH * 2 + in], 0, 0, 0);
}

template<int MODE>
__global__ __launch_bounds__(512)
void gemm256(const short* __restrict__ A, long lda,
             const short* __restrict__ B,          // Bt: N rows x K cols
             const float* __restrict__ bias,
             void* __restrict__ outp, long ldo, int ooff, int nreal,
             const float* __restrict__ gate, short* __restrict__ gate_bf,
             int K)
{
    __shared__ short As[2][256 * 64];   // 64 KiB
    __shared__ short Bs[2][256 * 64];   // 64 KiB
    const int t = threadIdx.x;
    const int lane = t & 63;
    const int w = t >> 6;
    const int wrow = w >> 2, wcol = w & 3;

    // T1: bijective XCD swizzle (all grids here have nwg % 8 == 0)
    const int gx = gridDim.x;
    int lin = blockIdx.y * gx + blockIdx.x;
    int q8 = (gx * gridDim.y) >> 3;
    int lin2 = (lin & 7) * q8 + (lin >> 3);
    const long bm = (long)(lin2 / gx) * 256;
    const long bn = (long)(lin2 % gx) * 256;

    const short* Ab = A + bm * lda;
    const short* Bb = B + bn * (long)K;

    // per-thread staging geometry (swizzled global source, linear LDS dest)
    const int tq = t >> 3;                       // 0..63
    const int scz = (t & 7) ^ (tq & 7);          // pre-swizzled chunk
    const long aoff = (long)tq * lda + scz * 8;
    const int  brw  = (tq >> 5) * 64 + (tq & 31);
    const long boff = (long)brw * K + scz * 8;
    const int  blds = brw * 8 + (t & 7);         // B per-thread LDS chunk idx

    const int fr = lane & 15, kc0 = lane >> 4;

    // A part p of K-tile `tile` -> buf: rows {p*64..p*64+64) and +128
    auto stgA = [&](int buf, int p, long tile) {
        long k0 = tile << 6;
        #pragma unroll
        for (int j = 0; j < 2; ++j) {
            int u = j * 128 + p * 64;
            async16(Ab + (long)u * lda + k0 + aoff, &As[buf][u * 64 + t * 8]);
        }
    };
    // B part p: rows with (r&63) in [p*32, p*32+32)
    auto stgB = [&](int buf, int p, long tile) {
        long k0 = tile << 6;
        #pragma unroll
        for (int j = 0; j < 2; ++j) {
            int u = j * 128 + p * 32;
            async16(Bb + (long)u * K + k0 + boff, &Bs[buf][u * 64 + blds * 8]);
        }
    };

    f32x4 acc[8][4] = {};
    bf16x8 a[4][2], b0[2][2], b1[2][2];

    const int NT = K >> 6, NI = NT >> 1;

    // prologue: tile0 complete (8 loads) + 3 parts of tile1 (6 loads) in flight
    stgA(0, 0, 0); stgB(0, 0, 0); stgA(0, 1, 0); stgB(0, 1, 0);
    stgA(1, 0, 1); stgB(1, 0, 1); stgA(1, 1, 1);
    VMW(6);                                      // tile0 landed (my wave)

    for (int it = 0; it < NI; ++it) {
        const long T0 = 2 * it, T1 = 2 * it + 1;
        const bool m0 = (T0 + 2 < NT), m1 = (T1 + 2 < NT);
        const bool last = (it == NI - 1);
        // ---- p1: quad(mh0,nh0) of T0 (buf0) ----
        BAR(); SCHED0();                         // all waves' T0 loads landed
        stgB(1, 1, T1);                          // Bs[1]NH1: last read prev-p6
        loadAf<0>(a, As[0], wrow, fr, kc0);
        loadBf<0>(b0, Bs[0], wcol, fr, kc0);
        __builtin_amdgcn_s_setprio(1); quadf<0, 0>(acc, a, b0); __builtin_amdgcn_s_setprio(0);
        // ---- p2: quad(mh0,nh1) ----
        BAR(); SCHED0();
        if (m0) stgA(0, 0, T0 + 2);              // As[0]MH0: last read p1
        loadBf<1>(b1, Bs[0], wcol, fr, kc0);
        __builtin_amdgcn_s_setprio(1); quadf<0, 1>(acc, a, b1); __builtin_amdgcn_s_setprio(0);
        // ---- p3: quad(mh1,nh0) ----
        BAR(); SCHED0();
        if (m0) stgB(0, 0, T0 + 2);              // Bs[0]NH0: last read p1
        loadAf<1>(a, As[0], wrow, fr, kc0);
        __builtin_amdgcn_s_setprio(1); quadf<1, 0>(acc, a, b0); __builtin_amdgcn_s_setprio(0);
        // ---- p4: quad(mh1,nh1); then counted wait -> T1 landed (my wave) ----
        BAR(); SCHED0();
        if (m0) stgA(0, 1, T0 + 2);              // As[0]MH1: last read p3
        __builtin_amdgcn_s_setprio(1); quadf<1, 1>(acc, a, b1); __builtin_amdgcn_s_setprio(0);
        if (last) { VMW(0); } else { VMW(6); }
        // ---- p5: quad(mh0,nh0) of T1 (buf1) ----
        BAR(); SCHED0();                         // all waves' T1 loads landed
        if (m0) stgB(0, 1, T0 + 2);              // Bs[0]NH1: last read p2
        loadAf<0>(a, As[1], wrow, fr, kc0);
        loadBf<0>(b0, Bs[1], wcol, fr, kc0);
        __builtin_amdgcn_s_setprio(1); quadf<0, 0>(acc, a, b0); __builtin_amdgcn_s_setprio(0);
        // ---- p6 ----
        BAR(); SCHED0();
        if (m1) stgA(1, 0, T1 + 2);              // As[1]MH0: last read p5
        loadBf<1>(b1, Bs[1], wcol, fr, kc0);
        __builtin_amdgcn_s_setprio(1); quadf<0, 1>(acc, a, b1); __builtin_amdgcn_s_setprio(0);
        // ---- p7 ----
        BAR(); SCHED0();
        if (m1) stgB(1, 0, T1 + 2);              // Bs[1]NH0: last read p5
        loadAf<1>(a, As[1], wrow, fr, kc0);
        __builtin_amdgcn_s_setprio(1); quadf<1, 0>(acc, a, b0); __builtin_amdgcn_s_setprio(0);
        // ---- p8: quad; counted wait -> T0+2 landed (my wave) ----
        BAR(); SCHED0();
        if (m1) stgA(1, 1, T1 + 2);              // As[1]MH1: last read p7
        __builtin_amdgcn_s_setprio(1); quadf<1, 1>(acc, a, b1); __builtin_amdgcn_s_setprio(0);
        if (last) { VMW(0); } else { VMW(6); }
    }

    // epilogue: C/D layout col=lane&15, row=(lane>>4)*4+reg.
    // in-innermost: the 4 stores of a row hit one 128B line back-to-back.
    const int col = lane & 15, rb = (lane >> 4) * 4;
    float bv[4];
    #pragma unroll
    for (int in = 0; in < 4; ++in) {
        long n = bn + wcol * 64 + in * 16 + col;
        bv[in] = (n < nreal) ? bias[n] : 0.f;
    }
    #pragma unroll
    for (int im = 0; im < 8; ++im) {
        #pragma unroll
        for (int r = 0; r < 4; ++r) {
            long m = bm + wrow * 128 + im * 16 + rb + r;
            #pragma unroll
            for (int in = 0; in < 4; ++in) {
                long n = bn + wcol * 64 + in * 16 + col;
                if (n >= nreal) continue;
                float v = acc[im][in][r] + bv[in];
                if (MODE == 1) v = fmaxf(v, 0.f);
                if (MODE == 2) {
                    float g = gate[m * 4096 + n];
                    gate_bf[m * 4096 + n] = f2bf(g);
                    v = fmaxf(v * g, 0.f);
                }
                ((short*)outp)[m * ldo + ooff + n] = f2bf(v);
            }
        }
    }
}

// ---------------- small kernels ---------------------------------------------
__global__ void cvt_bf16(const float* __restrict__ in, short* __restrict__ out, long n) {
    long i = (long)blockIdx.x * 256 + threadIdx.x;
    if (i < n) out[i] = f2bf(in[i]);
}

// out[c][r] = in[r][c] as bf16, zero pad to (Cp,Rp); Cp,Rp multiples of 32
__global__ __launch_bounds__(256)
void transpose_pad(const float* __restrict__ in, int R, int C,
                   short* __restrict__ out, int Cp, int Rp)
{
    __shared__ float tile[32][33];
    int tx = threadIdx.x, ty = threadIdx.y;
    int c0 = blockIdx.x * 32, r0 = blockIdx.y * 32;
    #pragma unroll
    for (int j = 0; j < 32; j += 8) {
        int r = r0 + ty + j, c = c0 + tx;
        tile[ty + j][tx] = (r < R && c < C) ? in[(long)r * C + c] : 0.f;
    }
    __syncthreads();
    #pragma unroll
    for (int j = 0; j < 32; j += 8) {
        int oc = c0 + ty + j;   // output row (= input col)
        int orr = r0 + tx;      // output col (= input row)
        out[(long)oc * Rp + orr] = f2bf(tile[tx][ty + j]);
    }
}

// wF (128 x 5120) = [w_rel ; w_ctx]^T bf16 (rows>=51 zero), biasF = b_rel+b_ctx
__global__ void build_wf(const float* __restrict__ w_rel, const float* __restrict__ b_rel,
                         const float* __restrict__ w_ctx, const float* __restrict__ b_ctx,
                         short* __restrict__ wf, float* __restrict__ biasF)
{
    long i = (long)blockIdx.x * 256 + threadIdx.x;   // 128*5120 total
    if (i < 64) biasF[i] = (i < 51) ? b_rel[i] + b_ctx[i] : 0.f;
    if (i >= 128L * 5120) return;
    int n = (int)(i / 5120), k = (int)(i % 5120);
    float v = 0.f;
    if (n < 51) v = (k < 4096) ? w_rel[(long)k * 51 + n] : w_ctx[(long)(k - 4096) * 51 + n];
    wf[i] = f2bf(v);
}

// prod_rep gather -> vrcat cols [4096,5120), plus freq index
__global__ void gather_prod(const short* __restrict__ erep, const int* __restrict__ pairs,
                            const int* __restrict__ obj_preds,
                            short* __restrict__ vrcat, int* __restrict__ fidx)
{
    long i = blockIdx.x;
    int t = threadIdx.x;
    int s = pairs[2 * i], o = pairs[2 * i + 1];
    if (t == 0) fidx[i] = obj_preds[s] * 151 + obj_preds[o];
    int c = t * 4;
    long src = (long)(c < 512 ? s : o) * 1024 + c;
    *(uint2*)(vrcat + i * 5120 + 4096 + c) = *(const uint2*)(erep + src);
}

// column sums of tmp[:, 0:200] (u and v) into colsum[0:200]
__global__ void colsum200(const short* __restrict__ tmp, float* __restrict__ colsum) {
    int t = threadIdx.x;
    if (t >= 200) return;
    const short* p = tmp + (long)blockIdx.x * 128 * 400 + t;
    float s = 0.f;
    for (int r = 0; r < 128; ++r) s += bf2f(p[(long)r * 400]);
    atomicAdd(&colsum[t], s);
}

// d = 1/( (colsum_u . colsum_v)/16384 + 1e-6 )
__global__ void compute_d(const float* __restrict__ cs, float* __restrict__ dout) {
    int t = threadIdx.x;  // 64
    float v = cs[t] * cs[100 + t];
    if (t < 36) v += cs[64 + t] * cs[164 + t];
    #pragma unroll
    for (int m = 32; m >= 1; m >>= 1) v += __shfl_xor(v, m, 64);
    if (t == 0) dout[0] = 1.f / (v / 16384.f + 1e-6f);
}

// vtz[100,100] += v_chunk^T @ z_chunk  (64 rows per block, f32 atomics)
__global__ __launch_bounds__(256)
void vtz_kern(const short* __restrict__ tmp, float* __restrict__ vtz) {
    __shared__ float vs[64 * 100];
    __shared__ float zs[64 * 100];
    int t = threadIdx.x;
    long r0 = (long)blockIdx.x * 64;
    for (int i = t; i < 64 * 200; i += 256) {
        int r = i / 200, c = i % 200;
        float val = bf2f(tmp[(r0 + r) * 400 + 100 + c]);
        if (c < 100) vs[r * 100 + c] = val; else zs[r * 100 + (c - 100)] = val;
    }
    __syncthreads();
    for (int e = t; e < 10000; e += 256) {
        int k = e / 100, l = e % 100;
        float s = 0.f;
        #pragma unroll 4
        for (int r = 0; r < 64; ++r) s += vs[r * 100 + k] * zs[r * 100 + l];
        atomicAdd(&vtz[e], s);
    }
}

// xcat[:,0:100]=relu(d * u@vtz); xcat[:,100:200]=t-part; xcat[:,4296:4352]=0
__global__ __launch_bounds__(256)
void res_kern(const short* __restrict__ tmp, const float* __restrict__ vtz,
              const float* __restrict__ dptr, short* __restrict__ xcat)
{
    __shared__ float vt[10000];
    __shared__ float us[32 * 100];
    int t = threadIdx.x;
    long r0 = (long)blockIdx.x * 32;
    for (int i = t; i < 10000; i += 256) vt[i] = vtz[i];
    for (int i = t; i < 3200; i += 256) {
        int r = i / 100, c = i % 100;
        us[i] = bf2f(tmp[(r0 + r) * 400 + c]);
    }
    __syncthreads();
    float d = dptr[0];
    for (int e = t; e < 3200; e += 256) {
        int r = e / 100, c = e % 100;
        float s = 0.f;
        #pragma unroll 4
        for (int k = 0; k < 100; ++k) s += us[r * 100 + k] * vt[k * 100 + c];
        xcat[(r0 + r) * 4352 + c] = f2bf(fmaxf(s * d, 0.f));
    }
    for (int e = t; e < 3200; e += 256) {
        int r = e / 100, c = e % 100;
        xcat[(r0 + r) * 4352 + 100 + c] = tmp[(r0 + r) * 400 + 300 + c];
    }
    for (int e = t; e < 32 * 56; e += 256) {
        int r = e / 56, c = e % 56;
        xcat[(r0 + r) * 4352 + 4296 + c] = 0;
    }
}

// group-norm(8 groups of 512) over relu'd y; writes x_gn bf16 and relu -> x2cat
__global__ __launch_bounds__(256)
void gn_kern(const short* __restrict__ y, const float* __restrict__ gamma,
             const float* __restrict__ beta,
             short* __restrict__ xgn, short* __restrict__ x2cat)
{
    long row = blockIdx.x;
    int t = threadIdx.x;                   // thread t -> cols [16t,16t+16)
    const short* p = y + row * 4096 + t * 16;
    const uint4* q = (const uint4*)p;
    uint4 q0 = q[0], q1 = q[1];
    unsigned u[8] = {q0.x, q0.y, q0.z, q0.w, q1.x, q1.y, q1.z, q1.w};
    float v[16];
    #pragma unroll
    for (int i = 0; i < 8; ++i) {
        v[2 * i]     = __uint_as_float(u[i] << 16);
        v[2 * i + 1] = __uint_as_float(u[i] & 0xFFFF0000u);
    }
    float s1 = 0.f, s2 = 0.f;
    #pragma unroll
    for (int i = 0; i < 16; ++i) { s1 += v[i]; s2 += v[i] * v[i]; }
    // one group = 512 cols = 32 consecutive lanes
    #pragma unroll
    for (int m = 1; m < 32; m <<= 1) { s1 += __shfl_xor(s1, m, 32); s2 += __shfl_xor(s2, m, 32); }
    float mu = s1 * (1.f / 512.f);
    float var = fmaxf(s2 * (1.f / 512.f) - mu * mu, 0.f);
    float rs = rsqrtf(var + 1e-5f);
    #pragma unroll
    for (int i = 0; i < 16; ++i) {
        int c = t * 16 + i;
        float val = (v[i] - mu) * rs * gamma[c] + beta[c];
        xgn[row * 4096 + c] = f2bf(val);
        x2cat[row * 4352 + 200 + c] = f2bf(fmaxf(val, 0.f));
    }
}

// ---------------- orchestration ---------------------------------------------
extern "C" void kernel_launch(void* const* d_in, const int* in_sizes, int n_in,
                              void* d_out, int out_size, void* d_ws, size_t ws_size,
                              hipStream_t stream)
{
    (void)in_sizes; (void)n_in; (void)out_size; (void)ws_size;
    const float* edge_ctx   = (const float*)d_in[0];
    const float* unionf     = (const float*)d_in[1];
    const int*   pairs      = (const int*)d_in[2];
    const int*   obj_preds  = (const int*)d_in[3];
    const float* w_post_emb = (const float*)d_in[4];
    const float* b_post_emb = (const float*)d_in[5];
    const float* w_post_cat = (const float*)d_in[6];
    const float* b_post_cat = (const float*)d_in[7];
    const float* w_attn1    = (const float*)d_in[8];
    const float* b_attn1    = (const float*)d_in[9];
    const float* w_dr1      = (const float*)d_in[10];
    const float* b_dr1      = (const float*)d_in[11];
    const float* gamma      = (const float*)d_in[12];
    const float* beta       = (const float*)d_in[13];
    const float* w_attn2    = (const float*)d_in[14];
    const float* b_attn2    = (const float*)d_in[15];
    const float* w_dr2      = (const float*)d_in[16];
    const float* b_dr2      = (const float*)d_in[17];
    const float* w_rel      = (const float*)d_in[18];
    const float* b_rel      = (const float*)d_in[19];
    const float* w_ctx      = (const float*)d_in[20];
    const float* b_ctx      = (const float*)d_in[21];
    const float* freq       = (const float*)d_in[22];

    char* base = (char*)d_ws;
    size_t off = 0;
    auto alloc = [&](size_t b) -> void* {
        void* p = base + off; off += (b + 255) & ~(size_t)255; return p;
    };
    short* ec_bf  = (short*)alloc(4096L * 512 * 2);
    short* wTpe   = (short*)alloc(1024L * 512 * 2);
    short* erep   = (short*)alloc(4096L * 1024 * 2);
    short* vrcat  = (short*)alloc(16384L * 5120 * 2);  // [vr | prod_rep]
    int*   fidx   = (int*)  alloc(16384L * 4);
    short* ubf    = (short*)alloc(16384L * 4096 * 2);  // union bf16, later y1
    short* wTpc   = (short*)alloc(4096L * 1024 * 2);
    short* x1cat  = (short*)alloc(16384L * 4352 * 2);  // later x_gn
    short* wTa1   = (short*)alloc(512L * 4096 * 2);
    short* wTa2   = (short*)alloc(512L * 4096 * 2);
    short* tmp    = (short*)alloc(16384L * 400 * 2);
    short* wTd1   = (short*)alloc(4096L * 4352 * 2);
    short* wTd2   = (short*)alloc(4096L * 4352 * 2);
    short* x2cat  = (short*)alloc(16384L * 4352 * 2);
    short* wF     = (short*)alloc(128L * 5120 * 2);
    float* biasF  = (float*)alloc(64 * 4);
    float* colsum = (float*)alloc(400 * 4);
    float* vtz    = (float*)alloc(100 * 100 * 4);
    float* dval   = (float*)alloc(4);

    dim3 tb(32, 8);
    // weight prep (per launch: inputs restored, ws poisoned each timed call)
    cvt_bf16<<<(4096 * 512 + 255) / 256, 256, 0, stream>>>(edge_ctx, ec_bf, 4096L * 512);
    transpose_pad<<<dim3(1024 / 32, 512 / 32), tb, 0, stream>>>(w_post_emb, 512, 1024, wTpe, 1024, 512);
    transpose_pad<<<dim3(4096 / 32, 1024 / 32), tb, 0, stream>>>(w_post_cat, 1024, 4096, wTpc, 4096, 1024);
    transpose_pad<<<dim3(512 / 32, 4096 / 32), tb, 0, stream>>>(w_attn1, 4096, 400, wTa1, 512, 4096);
    transpose_pad<<<dim3(512 / 32, 4096 / 32), tb, 0, stream>>>(w_attn2, 4096, 400, wTa2, 512, 4096);
    transpose_pad<<<dim3(4096 / 32, 4352 / 32), tb, 0, stream>>>(w_dr1, 4296, 4096, wTd1, 4096, 4352);
    transpose_pad<<<dim3(4096 / 32, 4352 / 32), tb, 0, stream>>>(w_dr2, 4296, 4096, wTd2, 4096, 4352);
    build_wf<<<(128 * 5120 + 255) / 256, 256, 0, stream>>>(w_rel, b_rel, w_ctx, b_ctx, wF, biasF);

    // edge_rep = edge_ctx @ w_post_emb + b
    gemm128<0><<<dim3(8, 32), 256, 0, stream>>>(ec_bf, 512, wTpe, b_post_emb,
        erep, 1024, 0, 1024, nullptr, nullptr, nullptr, nullptr, 512);
    gather_prod<<<16384, 256, 0, stream>>>(erep, pairs, obj_preds, vrcat, fidx);

    // x_local1 = relu(union * (prod_rep@w_post_cat + b)); also union->bf16
    gemm256<2><<<dim3(16, 64), 512, 0, stream>>>(vrcat + 4096, 5120, wTpc, b_post_cat,
        x1cat, 4352, 200, 4096, unionf, ubf, 1024);

    // lrga1
    gemm128<1><<<dim3(4, 128), 256, 0, stream>>>(ubf, 4096, wTa1, b_attn1,
        tmp, 400, 0, 400, nullptr, nullptr, nullptr, nullptr, 4096);
    hipMemsetAsync(colsum, 0, 400 * 4, stream);
    hipMemsetAsync(vtz, 0, 100 * 100 * 4, stream);
    colsum200<<<128, 256, 0, stream>>>(tmp, colsum);
    compute_d<<<1, 64, 0, stream>>>(colsum, dval);
    vtz_kern<<<256, 256, 0, stream>>>(tmp, vtz);
    res_kern<<<512, 256, 0, stream>>>(tmp, vtz, dval, x1cat);

    // y1 = relu(x1cat @ w_dr1 + b)  -> reuse ubf
    gemm256<1><<<dim3(16, 64), 512, 0, stream>>>(x1cat, 4352, wTd1, b_dr1,
        ubf, 4096, 0, 4096, nullptr, nullptr, 4352);
    // group norm -> x_gn (reuse x1cat) + relu -> x2cat[:,200:4296]
    gn_kern<<<16384, 256, 0, stream>>>(ubf, gamma, beta, x1cat, x2cat);

    // lrga2
    gemm128<1><<<dim3(4, 128), 256, 0, stream>>>(x1cat, 4096, wTa2, b_attn2,
        tmp, 400, 0, 400, nullptr, nullptr, nullptr, nullptr, 4096);
    hipMemsetAsync(colsum, 0, 400 * 4, stream);
    hipMemsetAsync(vtz, 0, 100 * 100 * 4, stream);
    colsum200<<<128, 256, 0, stream>>>(tmp, colsum);
    compute_d<<<1, 64, 0, stream>>>(colsum, dval);
    vtz_kern<<<256, 256, 0, stream>>>(tmp, vtz);
    res_kern<<<512, 256, 0, stream>>>(tmp, vtz, dval, x2cat);

    // visual_rep = x2cat @ w_dr2 + b  -> vrcat[:,0:4096]
    gemm256<0><<<dim3(16, 64), 512, 0, stream>>>(x2cat, 4352, wTd2, b_dr2,
        vrcat, 5120, 0, 4096, nullptr, nullptr, 4352);
    // rel_dists = vrcat @ [w_rel;w_ctx] + b_rel + b_ctx + freq
    gemm128<3><<<dim3(1, 128), 256, 0, stream>>>(vrcat, 5120, wF, biasF,
        d_out, 51, 0, 51, nullptr, nullptr, fidx, freq, 5120);
}

// Round 3
// 2551.957 us; speedup vs baseline: 1.0862x; 1.0862x over previous
//
#include <hip/hip_runtime.h>

// ---------------- bf16 helpers (bit-level, no header dependency) ------------
__device__ __forceinline__ short f2bf(float f) {       // RNE f32 -> bf16
    unsigned u = __float_as_uint(f);
    unsigned r = (u + 0x7FFFu + ((u >> 16) & 1u)) >> 16;
    return (short)r;
}
__device__ __forceinline__ float bf2f(short s) {
    return __uint_as_float(((unsigned)(unsigned short)s) << 16);
}

typedef short bf16x8 __attribute__((ext_vector_type(8)));
typedef float f32x4  __attribute__((ext_vector_type(4)));

// async global->LDS, 16B per lane (wave-uniform LDS base + lane*16)
__device__ __forceinline__ void async16(const void* g, void* l) {
    __builtin_amdgcn_global_load_lds(
        (__attribute__((address_space(1))) unsigned int*)(void*)(g),
        (__attribute__((address_space(3))) unsigned int*)(l), 16, 0, 0);
}

// 32-bit LDS byte address (for inline-asm ds_read vaddr)
__device__ __forceinline__ unsigned ldsaddr(const void* p) {
    return (unsigned)(unsigned long long)
        (__attribute__((address_space(3))) const void*)p;
}

#define BAR()    __builtin_amdgcn_s_barrier()
#define SCHED0() __builtin_amdgcn_sched_barrier(0)
#define LGKM0()  asm volatile("s_waitcnt lgkmcnt(0)" ::: "memory")
#define VMW(n)   asm volatile("s_waitcnt vmcnt(" #n ")" ::: "memory")
#define PRIO1()  __builtin_amdgcn_s_setprio(1)
#define PRIO0()  __builtin_amdgcn_s_setprio(0)

// single ds_read_b128 with literal byte offset (zero per-phase VALU)
#define DSR(d, va, off) \
    asm volatile("ds_read_b128 %0, %1 offset:" off : "=v"(d) : "v"(va))

// A fragment block: 8 reads, offsets o0..o3 = buf*32768 + MH*8192 + im*2048
#define LDA8(o0, o1, o2, o3) do { \
    DSR(a[0][0], avA0, o0); DSR(a[0][1], avA1, o0); \
    DSR(a[1][0], avA0, o1); DSR(a[1][1], avA1, o1); \
    DSR(a[2][0], avA0, o2); DSR(a[2][1], avA1, o2); \
    DSR(a[3][0], avA0, o3); DSR(a[3][1], avA1, o3); } while (0)
// B fragment block: 4 reads, offsets = buf*32768 + NH*4096 + in*2048
#define LDB4(bb, o0, o1) do { \
    DSR(bb[0][0], avB0, o0); DSR(bb[0][1], avB1, o0); \
    DSR(bb[1][0], avB0, o1); DSR(bb[1][1], avB1, o1); } while (0)

// ---------------- generic 128x128x(BK=64) bf16 MFMA GEMM --------------------
// (kept for the small GEMMs: erep, attn1/2 (N=400), final N=51)
// C[m,n] = sum_k A[m,k]*Bt[n,k] + bias[n], with per-MODE epilogue.
// LDS layout is XOR-swizzled in 16B chunks: LDS[r][c] = global[r][c^(r&7)]
// MODE 0: out bf16 = acc+bias
// MODE 1: out bf16 = relu(acc+bias)
// MODE 2: out bf16 = relu((acc+bias)*gate[m,n]); also gate_bf[m,n]=bf16(gate)
// MODE 3: out f32  = acc+bias+freq[fidx[m]*51+n]   (final, nreal=51)
template<int MODE>
__global__ __launch_bounds__(256)
void gemm128(const short* __restrict__ A, long lda,
             const short* __restrict__ B,          // Bt: N rows x K cols
             const float* __restrict__ bias,
             void* __restrict__ outp, long ldo, int ooff, int nreal,
             const float* __restrict__ gate, short* __restrict__ gate_bf,
             const int* __restrict__ fidx, const float* __restrict__ freq,
             int K)
{
    __shared__ short As[128 * 64];
    __shared__ short Bs[128 * 64];
    const int t = threadIdx.x;
    const int lane = t & 63;
    const int w = t >> 6;
    const long bm = (long)blockIdx.y * 128;
    const long bn = (long)blockIdx.x * 128;

    f32x4 acc[4][4] = {};

    const short* Ab = A + bm * lda;
    const short* Bb = B + bn * (long)K;

    const int wm = (w & 1) * 64, wn = (w >> 1) * 64;
    const int mrow = lane & 15, khi = (lane >> 4) * 8;
    const int swz = mrow & 7;          // row-dependent chunk swizzle

    for (int k0 = 0; k0 < K; k0 += 64) {
        __syncthreads();
        #pragma unroll
        for (int i = 0; i < 4; ++i) {
            int idx = i * 256 + t;
            int r = idx >> 3, ch = (idx & 7) ^ (r & 7);
            async16(Ab + (long)r * lda + (k0 + ch * 8), &As[idx * 8]);
        }
        #pragma unroll
        for (int i = 0; i < 4; ++i) {
            int idx = i * 256 + t;
            int r = idx >> 3, ch = (idx & 7) ^ (r & 7);
            async16(Bb + (long)r * K + (k0 + ch * 8), &Bs[idx * 8]);
        }
        __syncthreads();

        #pragma unroll
        for (int kk = 0; kk < 64; kk += 32) {
            const int ch = (((kk + khi) >> 3) ^ swz) * 8;
            bf16x8 a[4], b[4];
            #pragma unroll
            for (int im = 0; im < 4; ++im)
                a[im] = *(const bf16x8*)&As[(wm + im * 16 + mrow) * 64 + ch];
            #pragma unroll
            for (int in = 0; in < 4; ++in)
                b[in] = *(const bf16x8*)&Bs[(wn + in * 16 + mrow) * 64 + ch];
            #pragma unroll
            for (int im = 0; im < 4; ++im)
                #pragma unroll
                for (int in = 0; in < 4; ++in)
                    acc[im][in] = __builtin_amdgcn_mfma_f32_16x16x32_bf16(
                        a[im], b[in], acc[im][in], 0, 0, 0);
        }
    }

    const int col = lane & 15, rb = (lane >> 4) * 4;
    #pragma unroll
    for (int in = 0; in < 4; ++in) {
        long n = bn + wn + in * 16 + col;
        if (n >= nreal) continue;
        float bv = bias[n];
        #pragma unroll
        for (int im = 0; im < 4; ++im) {
            #pragma unroll
            for (int r = 0; r < 4; ++r) {
                long m = bm + wm + im * 16 + rb + r;
                float v = acc[im][in][r] + bv;
                if (MODE == 1) v = fmaxf(v, 0.f);
                if (MODE == 2) {
                    float g = gate[m * 4096 + n];
                    gate_bf[m * 4096 + n] = f2bf(g);
                    v = fmaxf(v * g, 0.f);
                }
                if (MODE == 3) {
                    v += freq[(long)fidx[m] * 51 + n];
                    ((float*)outp)[m * 51 + n] = v;
                } else {
                    ((short*)outp)[m * ldo + ooff + n] = f2bf(v);
                }
            }
        }
    }
}

// ------------- 256x256x(BK=64) 8-wave 8-phase pipelined bf16 GEMM -----------
// m201 2-barrier template; fragment reads are inline-asm ds_read_b128 off 4
// precomputed per-lane base addresses (A/B x kslot) + literal offset: imms
// (buf*32768 + MH*8192 + im*2048 for A; buf*32768 + NH*4096 + in*2048 for B)
// -> zero per-phase address VALU (r2 showed 223 VALU-cyc/SIMD/phase of
// address remat = the gap vs m201's 824 cyc/phase). Rule #18: every phase
// has lgkmcnt(0)+sched_barrier(0) between barrier and MFMAs.
template<int MH, int NH>
__device__ __forceinline__ void quadf(f32x4 (&acc)[8][4], const bf16x8 (&a)[4][2],
                                      const bf16x8 (&bb)[2][2]) {
    #pragma unroll
    for (int ks = 0; ks < 2; ++ks)
        #pragma unroll
        for (int im = 0; im < 4; ++im)
            #pragma unroll
            for (int in = 0; in < 2; ++in)
                acc[MH * 4 + im][NH * 2 + in] = __builtin_amdgcn_mfma_f32_16x16x32_bf16(
                    a[im][ks], bb[in][ks], acc[MH * 4 + im][NH * 2 + in], 0, 0, 0);
}

template<int MODE>
__global__ __launch_bounds__(512)
void gemm256(const short* __restrict__ A, long lda,
             const short* __restrict__ B,          // Bt: N rows x K cols
             const float* __restrict__ bias,
             void* __restrict__ outp, long ldo, int ooff, int nreal,
             const float* __restrict__ gate, short* __restrict__ gate_bf,
             int K)
{
    __shared__ short As[2][256 * 64];   // 64 KiB
    __shared__ short Bs[2][256 * 64];   // 64 KiB
    const int t = threadIdx.x;
    const int lane = t & 63;
    const int w = t >> 6;
    const int wrow = w >> 2, wcol = w & 3;

    // T1: bijective XCD swizzle (all grids here have nwg % 8 == 0)
    const int gx = gridDim.x;
    int lin = blockIdx.y * gx + blockIdx.x;
    int q8 = (gx * gridDim.y) >> 3;
    int lin2 = (lin & 7) * q8 + (lin >> 3);
    const long bm = (long)(lin2 / gx) * 256;
    const long bn = (long)(lin2 % gx) * 256;

    const short* Ab = A + bm * lda;
    const short* Bb = B + bn * (long)K;

    // per-thread staging geometry (swizzled global source, linear LDS dest)
    const int tq = t >> 3;                       // 0..63
    const int scz = (t & 7) ^ (tq & 7);          // pre-swizzled chunk
    const long aoff = (long)tq * lda + scz * 8;
    const int  brw  = (tq >> 5) * 64 + (tq & 31);
    const long boff = (long)brw * K + scz * 8;
    const int  blds = brw * 8 + (t & 7);         // B per-thread LDS chunk idx

    const int fr = lane & 15, kc0 = lane >> 4;

    // precomputed fragment-read base addresses (bytes into LDS), 4 VGPRs:
    // row_local byte = row*128, chunk byte = ((kcX)^(fr&7))*16
    const unsigned As0 = ldsaddr(&As[0][0]);
    const unsigned Bs0 = ldsaddr(&Bs[0][0]);
    const unsigned avA0 = As0 + wrow * 16384 + fr * 128 + (((kc0    ) ^ (fr & 7)) << 4);
    const unsigned avA1 = As0 + wrow * 16384 + fr * 128 + (((kc0 + 4) ^ (fr & 7)) << 4);
    const unsigned avB0 = Bs0 + wcol * 8192  + fr * 128 + (((kc0    ) ^ (fr & 7)) << 4);
    const unsigned avB1 = Bs0 + wcol * 8192  + fr * 128 + (((kc0 + 4) ^ (fr & 7)) << 4);

    // A part p of K-tile `tile` -> buf: rows {p*64..p*64+64) and +128
    auto stgA = [&](int buf, int p, long tile) {
        long k0 = tile << 6;
        #pragma unroll
        for (int j = 0; j < 2; ++j) {
            int u = j * 128 + p * 64;
            async16(Ab + (long)u * lda + k0 + aoff, &As[buf][u * 64 + t * 8]);
        }
    };
    // B part p: rows with (r&63) in [p*32, p*32+32)
    auto stgB = [&](int buf, int p, long tile) {
        long k0 = tile << 6;
        #pragma unroll
        for (int j = 0; j < 2; ++j) {
            int u = j * 128 + p * 32;
            async16(Bb + (long)u * K + k0 + boff, &Bs[buf][u * 64 + blds * 8]);
        }
    };

    f32x4 acc[8][4] = {};
    bf16x8 a[4][2], b0[2][2], b1[2][2];

    const int NT = K >> 6, NI = NT >> 1;

    // prologue: tile0 complete (8 loads) + 3 parts of tile1 (6 loads) in flight
    stgA(0, 0, 0); stgB(0, 0, 0); stgA(0, 1, 0); stgB(0, 1, 0);
    stgA(1, 0, 1); stgB(1, 0, 1); stgA(1, 1, 1);
    VMW(6);                                      // tile0 landed (my wave)
    BAR();                                       // all waves' tile0 landed

    for (int it = 0; it < NI; ++it) {
        const long T0 = 2 * it, T1 = 2 * it + 1;
        const bool m0 = (T0 + 2 < NT), m1 = (T1 + 2 < NT);
        const bool last = (it == NI - 1);
        // ---- p1: quad(mh0,nh0) of T0 (buf0) ----
        LDA8("0", "2048", "4096", "6144");
        LDB4(b0, "0", "2048");
        stgB(1, 1, T1);                          // Bs[1]NH1: last read prev-p6
        BAR(); LGKM0(); SCHED0();
        PRIO1(); quadf<0, 0>(acc, a, b0); PRIO0();
        BAR();
        // ---- p2: quad(mh0,nh1) ----
        LDB4(b1, "4096", "6144");
        if (m0) stgA(0, 0, T0 + 2);              // As[0]MH0: last read p1
        BAR(); LGKM0(); SCHED0();
        PRIO1(); quadf<0, 1>(acc, a, b1); PRIO0();
        BAR();
        // ---- p3: quad(mh1,nh0) ----
        LDA8("8192", "10240", "12288", "14336");
        if (m0) stgB(0, 0, T0 + 2);              // Bs[0]NH0: last read p1
        BAR(); LGKM0(); SCHED0();
        PRIO1(); quadf<1, 0>(acc, a, b0); PRIO0();
        BAR();
        // ---- p4: quad(mh1,nh1); counted wait -> T1 landed ----
        if (m0) stgA(0, 1, T0 + 2);              // As[0]MH1: last read p3
        if (last) { VMW(0); } else { VMW(6); }
        BAR(); SCHED0();
        PRIO1(); quadf<1, 1>(acc, a, b1); PRIO0();
        BAR();
        // ---- p5: quad(mh0,nh0) of T1 (buf1) ----
        LDA8("32768", "34816", "36864", "38912");
        LDB4(b0, "32768", "34816");
        if (m0) stgB(0, 1, T0 + 2);              // Bs[0]NH1: last read p2
        BAR(); LGKM0(); SCHED0();
        PRIO1(); quadf<0, 0>(acc, a, b0); PRIO0();
        BAR();
        // ---- p6 ----
        LDB4(b1, "36864", "38912");
        if (m1) stgA(1, 0, T1 + 2);              // As[1]MH0: last read p5
        BAR(); LGKM0(); SCHED0();
        PRIO1(); quadf<0, 1>(acc, a, b1); PRIO0();
        BAR();
        // ---- p7 ----
        LDA8("40960", "43008", "45056", "47104");
        if (m1) stgB(1, 0, T1 + 2);              // Bs[1]NH0: last read p5
        BAR(); LGKM0(); SCHED0();
        PRIO1(); quadf<1, 0>(acc, a, b0); PRIO0();
        BAR();
        // ---- p8: counted wait -> T0+2 landed ----
        if (m1) stgA(1, 1, T1 + 2);              // As[1]MH1: last read p7
        if (last) { VMW(0); } else { VMW(6); }
        BAR(); SCHED0();
        PRIO1(); quadf<1, 1>(acc, a, b1); PRIO0();
        BAR();
    }
    VMW(0);                                      // drain any stragglers

    // epilogue: C/D layout col=lane&15, row=(lane>>4)*4+reg.
    // in-innermost: the 4 stores of a row hit one 128B line back-to-back.
    const int col = lane & 15, rb = (lane >> 4) * 4;
    float bv[4];
    #pragma unroll
    for (int in = 0; in < 4; ++in) {
        long n = bn + wcol * 64 + in * 16 + col;
        bv[in] = (n < nreal) ? bias[n] : 0.f;
    }
    #pragma unroll
    for (int im = 0; im < 8; ++im) {
        #pragma unroll
        for (int r = 0; r < 4; ++r) {
            long m = bm + wrow * 128 + im * 16 + rb + r;
            #pragma unroll
            for (int in = 0; in < 4; ++in) {
                long n = bn + wcol * 64 + in * 16 + col;
                if (n >= nreal) continue;
                float v = acc[im][in][r] + bv[in];
                if (MODE == 1) v = fmaxf(v, 0.f);
                if (MODE == 2) {
                    float g = gate[m * 4096 + n];
                    gate_bf[m * 4096 + n] = f2bf(g);
                    v = fmaxf(v * g, 0.f);
                }
                ((short*)outp)[m * ldo + ooff + n] = f2bf(v);
            }
        }
    }
}

// ---------------- small kernels ---------------------------------------------
__global__ void cvt_bf16(const float* __restrict__ in, short* __restrict__ out, long n) {
    long i = (long)blockIdx.x * 256 + threadIdx.x;
    if (i < n) out[i] = f2bf(in[i]);
}

// out[c][r] = in[r][c] as bf16, zero pad to (Cp,Rp); Cp,Rp multiples of 32
__global__ __launch_bounds__(256)
void transpose_pad(const float* __restrict__ in, int R, int C,
                   short* __restrict__ out, int Cp, int Rp)
{
    __shared__ float tile[32][33];
    int tx = threadIdx.x, ty = threadIdx.y;
    int c0 = blockIdx.x * 32, r0 = blockIdx.y * 32;
    #pragma unroll
    for (int j = 0; j < 32; j += 8) {
        int r = r0 + ty + j, c = c0 + tx;
        tile[ty + j][tx] = (r < R && c < C) ? in[(long)r * C + c] : 0.f;
    }
    __syncthreads();
    #pragma unroll
    for (int j = 0; j < 32; j += 8) {
        int oc = c0 + ty + j;   // output row (= input col)
        int orr = r0 + tx;      // output col (= input row)
        out[(long)oc * Rp + orr] = f2bf(tile[tx][ty + j]);
    }
}

// wF (128 x 5120) = [w_rel ; w_ctx]^T bf16 (rows>=51 zero), biasF = b_rel+b_ctx
__global__ void build_wf(const float* __restrict__ w_rel, const float* __restrict__ b_rel,
                         const float* __restrict__ w_ctx, const float* __restrict__ b_ctx,
                         short* __restrict__ wf, float* __restrict__ biasF)
{
    long i = (long)blockIdx.x * 256 + threadIdx.x;   // 128*5120 total
    if (i < 64) biasF[i] = (i < 51) ? b_rel[i] + b_ctx[i] : 0.f;
    if (i >= 128L * 5120) return;
    int n = (int)(i / 5120), k = (int)(i % 5120);
    float v = 0.f;
    if (n < 51) v = (k < 4096) ? w_rel[(long)k * 51 + n] : w_ctx[(long)(k - 4096) * 51 + n];
    wf[i] = f2bf(v);
}

// prod_rep gather -> vrcat cols [4096,5120), plus freq index
__global__ void gather_prod(const short* __restrict__ erep, const int* __restrict__ pairs,
                            const int* __restrict__ obj_preds,
                            short* __restrict__ vrcat, int* __restrict__ fidx)
{
    long i = blockIdx.x;
    int t = threadIdx.x;
    int s = pairs[2 * i], o = pairs[2 * i + 1];
    if (t == 0) fidx[i] = obj_preds[s] * 151 + obj_preds[o];
    int c = t * 4;
    long src = (long)(c < 512 ? s : o) * 1024 + c;
    *(uint2*)(vrcat + i * 5120 + 4096 + c) = *(const uint2*)(erep + src);
}

// column sums of tmp[:, 0:200] (u and v) into colsum[0:200]
__global__ void colsum200(const short* __restrict__ tmp, float* __restrict__ colsum) {
    int t = threadIdx.x;
    if (t >= 200) return;
    const short* p = tmp + (long)blockIdx.x * 128 * 400 + t;
    float s = 0.f;
    for (int r = 0; r < 128; ++r) s += bf2f(p[(long)r * 400]);
    atomicAdd(&colsum[t], s);
}

// d = 1/( (colsum_u . colsum_v)/16384 + 1e-6 )
__global__ void compute_d(const float* __restrict__ cs, float* __restrict__ dout) {
    int t = threadIdx.x;  // 64
    float v = cs[t] * cs[100 + t];
    if (t < 36) v += cs[64 + t] * cs[164 + t];
    #pragma unroll
    for (int m = 32; m >= 1; m >>= 1) v += __shfl_xor(v, m, 64);
    if (t == 0) dout[0] = 1.f / (v / 16384.f + 1e-6f);
}

// vtz[100,100] += v_chunk^T @ z_chunk  (64 rows per block, f32 atomics)
__global__ __launch_bounds__(256)
void vtz_kern(const short* __restrict__ tmp, float* __restrict__ vtz) {
    __shared__ float vs[64 * 100];
    __shared__ float zs[64 * 100];
    int t = threadIdx.x;
    long r0 = (long)blockIdx.x * 64;
    for (int i = t; i < 64 * 200; i += 256) {
        int r = i / 200, c = i % 200;
        float val = bf2f(tmp[(r0 + r) * 400 + 100 + c]);
        if (c < 100) vs[r * 100 + c] = val; else zs[r * 100 + (c - 100)] = val;
    }
    __syncthreads();
    for (int e = t; e < 10000; e += 256) {
        int k = e / 100, l = e % 100;
        float s = 0.f;
        #pragma unroll 4
        for (int r = 0; r < 64; ++r) s += vs[r * 100 + k] * zs[r * 100 + l];
        atomicAdd(&vtz[e], s);
    }
}

// xcat[:,0:100]=relu(d * u@vtz); xcat[:,100:200]=t-part; xcat[:,4296:4352]=0
__global__ __launch_bounds__(256)
void res_kern(const short* __restrict__ tmp, const float* __restrict__ vtz,
              const float* __restrict__ dptr, short* __restrict__ xcat)
{
    __shared__ float vt[10000];
    __shared__ float us[32 * 100];
    int t = threadIdx.x;
    long r0 = (long)blockIdx.x * 32;
    for (int i = t; i < 10000; i += 256) vt[i] = vtz[i];
    for (int i = t; i < 3200; i += 256) {
        int r = i / 100, c = i % 100;
        us[i] = bf2f(tmp[(r0 + r) * 400 + c]);
    }
    __syncthreads();
    float d = dptr[0];
    for (int e = t; e < 3200; e += 256) {
        int r = e / 100, c = e % 100;
        float s = 0.f;
        #pragma unroll 4
        for (int k = 0; k < 100; ++k) s += us[r * 100 + k] * vt[k * 100 + c];
        xcat[(r0 + r) * 4352 + c] = f2bf(fmaxf(s * d, 0.f));
    }
    for (int e = t; e < 3200; e += 256) {
        int r = e / 100, c = e % 100;
        xcat[(r0 + r) * 4352 + 100 + c] = tmp[(r0 + r) * 400 + 300 + c];
    }
    for (int e = t; e < 32 * 56; e += 256) {
        int r = e / 56, c = e % 56;
        xcat[(r0 + r) * 4352 + 4296 + c] = 0;
    }
}

// group-norm(8 groups of 512) over relu'd y; writes x_gn bf16 and relu -> x2cat
__global__ __launch_bounds__(256)
void gn_kern(const short* __restrict__ y, const float* __restrict__ gamma,
             const float* __restrict__ beta,
             short* __restrict__ xgn, short* __restrict__ x2cat)
{
    long row = blockIdx.x;
    int t = threadIdx.x;                   // thread t -> cols [16t,16t+16)
    const short* p = y + row * 4096 + t * 16;
    const uint4* q = (const uint4*)p;
    uint4 q0 = q[0], q1 = q[1];
    unsigned u[8] = {q0.x, q0.y, q0.z, q0.w, q1.x, q1.y, q1.z, q1.w};
    float v[16];
    #pragma unroll
    for (int i = 0; i < 8; ++i) {
        v[2 * i]     = __uint_as_float(u[i] << 16);
        v[2 * i + 1] = __uint_as_float(u[i] & 0xFFFF0000u);
    }
    float s1 = 0.f, s2 = 0.f;
    #pragma unroll
    for (int i = 0; i < 16; ++i) { s1 += v[i]; s2 += v[i] * v[i]; }
    // one group = 512 cols = 32 consecutive lanes
    #pragma unroll
    for (int m = 1; m < 32; m <<= 1) { s1 += __shfl_xor(s1, m, 32); s2 += __shfl_xor(s2, m, 32); }
    float mu = s1 * (1.f / 512.f);
    float var = fmaxf(s2 * (1.f / 512.f) - mu * mu, 0.f);
    float rs = rsqrtf(var + 1e-5f);
    #pragma unroll
    for (int i = 0; i < 16; ++i) {
        int c = t * 16 + i;
        float val = (v[i] - mu) * rs * gamma[c] + beta[c];
        xgn[row * 4096 + c] = f2bf(val);
        x2cat[row * 4352 + 200 + c] = f2bf(fmaxf(val, 0.f));
    }
}

// ---------------- orchestration ---------------------------------------------
extern "C" void kernel_launch(void* const* d_in, const int* in_sizes, int n_in,
                              void* d_out, int out_size, void* d_ws, size_t ws_size,
                              hipStream_t stream)
{
    (void)in_sizes; (void)n_in; (void)out_size; (void)ws_size;
    const float* edge_ctx   = (const float*)d_in[0];
    const float* unionf     = (const float*)d_in[1];
    const int*   pairs      = (const int*)d_in[2];
    const int*   obj_preds  = (const int*)d_in[3];
    const float* w_post_emb = (const float*)d_in[4];
    const float* b_post_emb = (const float*)d_in[5];
    const float* w_post_cat = (const float*)d_in[6];
    const float* b_post_cat = (const float*)d_in[7];
    const float* w_attn1    = (const float*)d_in[8];
    const float* b_attn1    = (const float*)d_in[9];
    const float* w_dr1      = (const float*)d_in[10];
    const float* b_dr1      = (const float*)d_in[11];
    const float* gamma      = (const float*)d_in[12];
    const float* beta       = (const float*)d_in[13];
    const float* w_attn2    = (const float*)d_in[14];
    const float* b_attn2    = (const float*)d_in[15];
    const float* w_dr2      = (const float*)d_in[16];
    const float* b_dr2      = (const float*)d_in[17];
    const float* w_rel      = (const float*)d_in[18];
    const float* b_rel      = (const float*)d_in[19];
    const float* w_ctx      = (const float*)d_in[20];
    const float* b_ctx      = (const float*)d_in[21];
    const float* freq       = (const float*)d_in[22];

    char* base = (char*)d_ws;
    size_t off = 0;
    auto alloc = [&](size_t b) -> void* {
        void* p = base + off; off += (b + 255) & ~(size_t)255; return p;
    };
    short* ec_bf  = (short*)alloc(4096L * 512 * 2);
    short* wTpe   = (short*)alloc(1024L * 512 * 2);
    short* erep   = (short*)alloc(4096L * 1024 * 2);
    short* vrcat  = (short*)alloc(16384L * 5120 * 2);  // [vr | prod_rep]
    int*   fidx   = (int*)  alloc(16384L * 4);
    short* ubf    = (short*)alloc(16384L * 4096 * 2);  // union bf16, later y1
    short* wTpc   = (short*)alloc(4096L * 1024 * 2);
    short* x1cat  = (short*)alloc(16384L * 4352 * 2);  // later x_gn
    short* wTa1   = (short*)alloc(512L * 4096 * 2);
    short* wTa2   = (short*)alloc(512L * 4096 * 2);
    short* tmp    = (short*)alloc(16384L * 400 * 2);
    short* wTd1   = (short*)alloc(4096L * 4352 * 2);
    short* wTd2   = (short*)alloc(4096L * 4352 * 2);
    short* x2cat  = (short*)alloc(16384L * 4352 * 2);
    short* wF     = (short*)alloc(128L * 5120 * 2);
    float* biasF  = (float*)alloc(64 * 4);
    float* colsum = (float*)alloc(400 * 4);
    float* vtz    = (float*)alloc(100 * 100 * 4);
    float* dval   = (float*)alloc(4);

    dim3 tb(32, 8);
    // weight prep (per launch: inputs restored, ws poisoned each timed call)
    cvt_bf16<<<(4096 * 512 + 255) / 256, 256, 0, stream>>>(edge_ctx, ec_bf, 4096L * 512);
    transpose_pad<<<dim3(1024 / 32, 512 / 32), tb, 0, stream>>>(w_post_emb, 512, 1024, wTpe, 1024, 512);
    transpose_pad<<<dim3(4096 / 32, 1024 / 32), tb, 0, stream>>>(w_post_cat, 1024, 4096, wTpc, 4096, 1024);
    transpose_pad<<<dim3(512 / 32, 4096 / 32), tb, 0, stream>>>(w_attn1, 4096, 400, wTa1, 512, 4096);
    transpose_pad<<<dim3(512 / 32, 4096 / 32), tb, 0, stream>>>(w_attn2, 4096, 400, wTa2, 512, 4096);
    transpose_pad<<<dim3(4096 / 32, 4352 / 32), tb, 0, stream>>>(w_dr1, 4296, 4096, wTd1, 4096, 4352);
    transpose_pad<<<dim3(4096 / 32, 4352 / 32), tb, 0, stream>>>(w_dr2, 4296, 4096, wTd2, 4096, 4352);
    build_wf<<<(128 * 5120 + 255) / 256, 256, 0, stream>>>(w_rel, b_rel, w_ctx, b_ctx, wF, biasF);

    // edge_rep = edge_ctx @ w_post_emb + b
    gemm128<0><<<dim3(8, 32), 256, 0, stream>>>(ec_bf, 512, wTpe, b_post_emb,
        erep, 1024, 0, 1024, nullptr, nullptr, nullptr, nullptr, 512);
    gather_prod<<<16384, 256, 0, stream>>>(erep, pairs, obj_preds, vrcat, fidx);

    // x_local1 = relu(union * (prod_rep@w_post_cat + b)); also union->bf16
    gemm256<2><<<dim3(16, 64), 512, 0, stream>>>(vrcat + 4096, 5120, wTpc, b_post_cat,
        x1cat, 4352, 200, 4096, unionf, ubf, 1024);

    // lrga1
    gemm128<1><<<dim3(4, 128), 256, 0, stream>>>(ubf, 4096, wTa1, b_attn1,
        tmp, 400, 0, 400, nullptr, nullptr, nullptr, nullptr, 4096);
    hipMemsetAsync(colsum, 0, 400 * 4, stream);
    hipMemsetAsync(vtz, 0, 100 * 100 * 4, stream);
    colsum200<<<128, 256, 0, stream>>>(tmp, colsum);
    compute_d<<<1, 64, 0, stream>>>(colsum, dval);
    vtz_kern<<<256, 256, 0, stream>>>(tmp, vtz);
    res_kern<<<512, 256, 0, stream>>>(tmp, vtz, dval, x1cat);

    // y1 = relu(x1cat @ w_dr1 + b)  -> reuse ubf
    gemm256<1><<<dim3(16, 64), 512, 0, stream>>>(x1cat, 4352, wTd1, b_dr1,
        ubf, 4096, 0, 4096, nullptr, nullptr, 4352);
    // group norm -> x_gn (reuse x1cat) + relu -> x2cat[:,200:4296]
    gn_kern<<<16384, 256, 0, stream>>>(ubf, gamma, beta, x1cat, x2cat);

    // lrga2
    gemm128<1><<<dim3(4, 128), 256, 0, stream>>>(x1cat, 4096, wTa2, b_attn2,
        tmp, 400, 0, 400, nullptr, nullptr, nullptr, nullptr, 4096);
    hipMemsetAsync(colsum, 0, 400 * 4, stream);
    hipMemsetAsync(vtz, 0, 100 * 100 * 4, stream);
    colsum200<<<128, 256, 0, stream>>>(tmp, colsum);
    compute_d<<<1, 64, 0, stream>>>(colsum, dval);
    vtz_kern<<<256, 256, 0, stream>>>(tmp, vtz);
    res_kern<<<512, 256, 0, stream>>>(tmp, vtz, dval, x2cat);

    // visual_rep = x2cat @ w_dr2 + b  -> vrcat[:,0:4096]
    gemm256<0><<<dim3(16, 64), 512, 0, stream>>>(x2cat, 4352, wTd2, b_dr2,
        vrcat, 5120, 0, 4096, nullptr, nullptr, 4352);
    // rel_dists = vrcat @ [w_rel;w_ctx] + b_rel + b_ctx + freq
    gemm128<3><<<dim3(1, 128), 256, 0, stream>>>(vrcat, 5120, wF, biasF,
        d_out, 51, 0, 51, nullptr, nullptr, fidx, freq, 5120);
}